// Round 3
// baseline (1988.401 us; speedup 1.0000x reference)
//
#include <hip/hip_runtime.h>

typedef unsigned short u16;
typedef __attribute__((ext_vector_type(8))) short short8;
typedef __attribute__((ext_vector_type(4))) float f32x4;

constexpr int SA    = 168;          // act row stride (bf16): 336B = 21x16B, lane stride == 20 banks (2-way, free)
constexpr int SW    = 168;          // weight row stride (global, bf16)
constexpr int NPAD  = 160;
constexpr int WSLOT = NPAD * SW;    // per-layer weight slot (elems)
constexpr int BLK_E = 128;          // edges per block
constexpr int NTHR  = 128;          // 2 waves; each wave: M=64 x N=full(160)

__device__ __forceinline__ u16 f2bf(float f) {  // RNE f32->bf16
    union { float f; unsigned u; } c; c.f = f;
    return (u16)((c.u + 0x7fffu + ((c.u >> 16) & 1u)) >> 16);
}

// k-storage permutation for hidden-layer activations:
//  logical n = j*16+col  ->  k' = col*8+j (j<8) | 128 + col*2 + (j-8) (j=8,9)
__device__ __forceinline__ int kperm(int kp) {
    if (kp < 128) return (kp & 7) * 16 + (kp >> 3);
    if (kp < 160) { const int m = kp - 128; return (8 + (m & 1)) * 16 + (m >> 1); }
    return 1 << 30;
}

// ---- prep: W[DI][DO] fp32 -> Wt[n][k'] bf16, zero-padded to [160][168] ----
__global__ void prep_weights(const float* __restrict__ W0, const float* __restrict__ W1,
                             const float* __restrict__ W2, const float* __restrict__ W3,
                             const float* __restrict__ W4, u16* __restrict__ out)
{
    const int l = blockIdx.y;
    const float* W; int DI, DO; bool perm;
    if      (l == 0) { W = W0; DI = 13;  DO = 150; perm = false; }
    else if (l == 1) { W = W1; DI = 150; DO = 150; perm = true;  }
    else if (l == 2) { W = W2; DI = 150; DO = 150; perm = true;  }
    else if (l == 3) { W = W3; DI = 150; DO = 150; perm = true;  }
    else             { W = W4; DI = 150; DO = 50;  perm = true;  }
    u16* dst = out + (size_t)l * WSLOT;
    for (int idx = blockIdx.x * blockDim.x + threadIdx.x; idx < WSLOT;
         idx += gridDim.x * blockDim.x) {
        const int n = idx / SW, kp = idx - n * SW;
        const int klog = perm ? kperm(kp) : kp;
        const float v = (n < DO && klog < DI) ? W[klog * DO + n] : 0.f;
        dst[idx] = f2bf(v);
    }
}

// ---- MFMA: wave = 4 M-tiles x NTH N-tiles (jbase offset), K = KS*32 --------
// A from LDS (own wave rows), B from global (L2-resident weights).
template<int KS, int NTH>
__device__ __forceinline__ void gemm_half(
    const u16* __restrict__ W, const u16* __restrict__ actw,
    int jbase, int col, int quad, f32x4 (&acc)[4][NTH])
{
#pragma unroll
    for (int i = 0; i < 4; ++i)
#pragma unroll
        for (int j = 0; j < NTH; ++j)
            acc[i][j] = f32x4{0.f, 0.f, 0.f, 0.f};

#pragma unroll
    for (int ks = 0; ks < KS; ++ks) {
        const int koff = ks * 32 + quad * 8;
        short8 Bf[NTH];
#pragma unroll
        for (int j = 0; j < NTH; ++j)
            Bf[j] = *(const short8*)&W[((jbase + j) * 16 + col) * SW + koff];
        short8 Af[4];
#pragma unroll
        for (int i = 0; i < 4; ++i)
            Af[i] = *(const short8*)&actw[(i * 16 + col) * SA + koff];
#pragma unroll
        for (int j = 0; j < NTH; ++j)
#pragma unroll
            for (int i = 0; i < 4; ++i)
                acc[i][j] = __builtin_amdgcn_mfma_f32_16x16x32_bf16(Af[i], Bf[j], acc[i][j], 0, 0, 0);
    }
}

// ---- epilogue half 0: j=0..7 -> one b128 per (i,r) at k' = col*8.. ----------
__device__ __forceinline__ void epi8(u16* actw, const float* __restrict__ bias,
                                     int col, int quad, f32x4 (&acc)[4][8])
{
    float bb[8];
#pragma unroll
    for (int j = 0; j < 8; ++j) {
        const int n = j * 16 + col;
        bb[j] = (n < 150) ? bias[n] : 0.f;
    }
#pragma unroll
    for (int i = 0; i < 4; ++i)
#pragma unroll
        for (int r = 0; r < 4; ++r) {
            short8 pk;
#pragma unroll
            for (int j = 0; j < 8; ++j)
                pk[j] = (short)f2bf(fmaxf(acc[i][j][r] + bb[j], 0.f));
            *(short8*)&actw[(i * 16 + quad * 4 + r) * SA + col * 8] = pk;
        }
}

// ---- epilogue half 1: j=8,9 -> one b32 per (i,r) at k' = 128 + col*2 --------
__device__ __forceinline__ void epi2(u16* actw, const float* __restrict__ bias,
                                     int col, int quad, f32x4 (&acc)[4][2])
{
    float bb[2];
#pragma unroll
    for (int j = 0; j < 2; ++j) {
        const int n = (8 + j) * 16 + col;
        bb[j] = (n < 150) ? bias[n] : 0.f;
    }
#pragma unroll
    for (int i = 0; i < 4; ++i)
#pragma unroll
        for (int r = 0; r < 4; ++r) {
            const u16 lo = f2bf(fmaxf(acc[i][0][r] + bb[0], 0.f));
            const u16 hi = f2bf(fmaxf(acc[i][1][r] + bb[1], 0.f));
            *(unsigned*)&actw[(i * 16 + quad * 4 + r) * SA + 128 + col * 2] =
                (unsigned)lo | ((unsigned)hi << 16);
        }
}

// ------------------------------- Edge kernel --------------------------------
__global__ __launch_bounds__(NTHR, 2) void edge_kernel(
    const float* __restrict__ t, const float* __restrict__ x, const float* __restrict__ Ofx,
    const int* __restrict__ src, const int* __restrict__ tgt,
    const u16* __restrict__ Wt,
    const float* __restrict__ B0, const float* __restrict__ B1, const float* __restrict__ B2,
    const float* __restrict__ B3, const float* __restrict__ B4,
    float* __restrict__ Ep, int n_edges)
{
    __shared__ __align__(16) u16 act[BLK_E * SA];    // 43008 B -> 3 blocks/CU
    __shared__ int tgt_s[BLK_E];

    const int tid  = threadIdx.x;
    const int lane = tid & 63;
    const int wv   = tid >> 6;          // wave id = M-group (64 edges each)
    const int col  = lane & 15;
    const int quad = lane >> 4;

    // ---- gather: one edge per thread, packed b128 LDS writes ----
    {
        const int e = tid;
        const long long ge = (long long)blockIdx.x * BLK_E + e;
        const bool valid = ge < n_edges;
        const int s = valid ? src[ge] : 0;
        const int g = valid ? tgt[ge] : 0;
        float v[16];
        const float4 xs = valid ? *(const float4*)&x[(size_t)s * 4] : float4{0, 0, 0, 0};
        const float2 os = valid ? *(const float2*)&Ofx[(size_t)s * 2] : float2{0, 0};
        const float4 xg = valid ? *(const float4*)&x[(size_t)g * 4] : float4{0, 0, 0, 0};
        const float2 og = valid ? *(const float2*)&Ofx[(size_t)g * 2] : float2{0, 0};
        v[0] = xs.x; v[1] = xs.y; v[2] = xs.z; v[3] = xs.w; v[4] = os.x; v[5] = os.y;
        v[6] = xg.x; v[7] = xg.y; v[8] = xg.z; v[9] = xg.w; v[10] = og.x; v[11] = og.y;
        v[12] = valid ? t[0] : 0.f; v[13] = v[14] = v[15] = 0.f;
        short8 c0, c1;
#pragma unroll
        for (int k = 0; k < 8; ++k) { c0[k] = (short)f2bf(v[k]); c1[k] = (short)f2bf(v[k + 8]); }
        u16* row = &act[e * SA];
        *(short8*)&row[0]  = c0;
        *(short8*)&row[8]  = c1;
        *(short8*)&row[16] = short8{0, 0, 0, 0, 0, 0, 0, 0};
        *(short8*)&row[24] = short8{0, 0, 0, 0, 0, 0, 0, 0};
        tgt_s[e] = valid ? g : -1;
    }
    __syncthreads();

    u16* actw = act + wv * 64 * SA;     // this wave's private 64 rows
    f32x4 acc8[4][8];
    f32x4 acc2[4][2];

    // L0: K=32 (13 real)
    gemm_half<1, 8>(Wt + 0 * WSLOT, actw, 0, col, quad, acc8);
    gemm_half<1, 2>(Wt + 0 * WSLOT, actw, 8, col, quad, acc2);
    epi8(actw, B0, col, quad, acc8);
    epi2(actw, B0, col, quad, acc2);
    __syncthreads();

    gemm_half<5, 8>(Wt + 1 * WSLOT, actw, 0, col, quad, acc8);   // L1
    gemm_half<5, 2>(Wt + 1 * WSLOT, actw, 8, col, quad, acc2);
    epi8(actw, B1, col, quad, acc8);
    epi2(actw, B1, col, quad, acc2);
    __syncthreads();

    gemm_half<5, 8>(Wt + 2 * WSLOT, actw, 0, col, quad, acc8);   // L2
    gemm_half<5, 2>(Wt + 2 * WSLOT, actw, 8, col, quad, acc2);
    epi8(actw, B2, col, quad, acc8);
    epi2(actw, B2, col, quad, acc2);
    __syncthreads();

    gemm_half<5, 8>(Wt + 3 * WSLOT, actw, 0, col, quad, acc8);   // L3
    gemm_half<5, 2>(Wt + 3 * WSLOT, actw, 8, col, quad, acc2);
    epi8(actw, B3, col, quad, acc8);
    epi2(actw, B3, col, quad, acc2);
    __syncthreads();

    // L4: 150 -> 50 (pad 64), linear; scatter from registers
    f32x4 acc4[4][4];
    gemm_half<5, 4>(Wt + 4 * WSLOT, actw, 0, col, quad, acc4);

#pragma unroll
    for (int j = 0; j < 4; ++j) {
        const int n = j * 16 + col;
        if (n < 50) {
            const float bb = B4[n];
#pragma unroll
            for (int i = 0; i < 4; ++i)
#pragma unroll
                for (int r = 0; r < 4; ++r) {
                    const int g = tgt_s[wv * 64 + i * 16 + quad * 4 + r];
                    if (g >= 0) atomicAdd(&Ep[(size_t)g * 50 + n], acc4[i][j][r] + bb);
                }
        }
    }
}

// ---------------- Node kernel (fp32 VALU — small cost) ----------------------
template<int DI, int DO, bool RELU>
__device__ __forceinline__ void mlp_layer_t(
    const float* __restrict__ W, const float* __restrict__ B,
    float (*in)[64], float (*out)[64], int tid)
{
    const int et = tid & 15;
    const int jt = tid >> 4;
    constexpr int NG = (DO + 15) / 16;

    float acc0[NG], acc1[NG], acc2[NG], acc3[NG];
#pragma unroll
    for (int g = 0; g < NG; ++g) {
        const int j = jt + 16 * g;
        const float bb = (j < DO) ? B[j] : 0.f;
        acc0[g] = bb; acc1[g] = bb; acc2[g] = bb; acc3[g] = bb;
    }
    for (int k = 0; k < DI; ++k) {
        const float4 a = *(const float4*)&in[k][et * 4];
#pragma unroll
        for (int g = 0; g < NG; ++g) {
            const int j = jt + 16 * g;
            const float wv = (j < DO) ? W[k * DO + j] : 0.f;
            acc0[g] = fmaf(a.x, wv, acc0[g]);
            acc1[g] = fmaf(a.y, wv, acc1[g]);
            acc2[g] = fmaf(a.z, wv, acc2[g]);
            acc3[g] = fmaf(a.w, wv, acc3[g]);
        }
    }
#pragma unroll
    for (int g = 0; g < NG; ++g) {
        const int j = jt + 16 * g;
        if (j < DO) {
            float4 v; v.x = acc0[g]; v.y = acc1[g]; v.z = acc2[g]; v.w = acc3[g];
            if (RELU) {
                v.x = fmaxf(v.x, 0.f); v.y = fmaxf(v.y, 0.f);
                v.z = fmaxf(v.z, 0.f); v.w = fmaxf(v.w, 0.f);
            }
            *(float4*)&out[j][et * 4] = v;
        }
    }
}

__global__ __launch_bounds__(256, 2) void node_kernel(
    const float* __restrict__ Eprime,
    const float* __restrict__ W0, const float* __restrict__ B0,
    const float* __restrict__ W1, const float* __restrict__ B1,
    float* __restrict__ P, int n_nodes)
{
    __shared__ float bufA[104][64];
    __shared__ float bufB[104][64];
    const int tid = threadIdx.x;
    const int n0  = blockIdx.x * 64;

    for (int idx = tid; idx < 64 * 50; idx += 256) {
        const int e = idx / 50;
        const int k = idx - e * 50;
        const int n = n0 + e;
        bufA[k][e] = (n < n_nodes) ? Eprime[(size_t)n * 50 + k] : 0.f;
    }
    __syncthreads();
    mlp_layer_t<50, 100, true >(W0, B0, bufA, bufB, tid); __syncthreads();
    mlp_layer_t<100, 4, false>(W1, B1, bufB, bufA, tid); __syncthreads();
    for (int idx = tid; idx < 64 * 4; idx += 256) {
        const int e = idx & 63;
        const int j = idx >> 6;
        const int n = n0 + e;
        if (n < n_nodes) P[(size_t)n * 4 + j] = bufA[j][e];
    }
}

// ------------------------------- launcher -----------------------------------
extern "C" void kernel_launch(void* const* d_in, const int* in_sizes, int n_in,
                              void* d_out, int out_size, void* d_ws, size_t ws_size,
                              hipStream_t stream)
{
    const float* t   = (const float*)d_in[0];
    const float* x   = (const float*)d_in[1];
    const float* Ofx = (const float*)d_in[2];
    const int*   src = (const int*)d_in[3];
    const int*   tgt = (const int*)d_in[4];
    const float* W0  = (const float*)d_in[5];  const float* B0 = (const float*)d_in[6];
    const float* W1  = (const float*)d_in[7];  const float* B1 = (const float*)d_in[8];
    const float* W2  = (const float*)d_in[9];  const float* B2 = (const float*)d_in[10];
    const float* W3  = (const float*)d_in[11]; const float* B3 = (const float*)d_in[12];
    const float* W4  = (const float*)d_in[13]; const float* B4 = (const float*)d_in[14];
    const float* OW0 = (const float*)d_in[15]; const float* OB0 = (const float*)d_in[16];
    const float* OW1 = (const float*)d_in[17]; const float* OB1 = (const float*)d_in[18];

    const int n_nodes = in_sizes[1] / 4;
    const int n_edges = in_sizes[3];

    float* Ep = (float*)d_ws;                                              // [N,50] fp32
    u16*   Wt = (u16*)((char*)d_ws + (size_t)n_nodes * 50 * sizeof(float)); // 5 slots

    prep_weights<<<dim3(32, 5), 256, 0, stream>>>(W0, W1, W2, W3, W4, Wt);
    hipMemsetAsync(Ep, 0, (size_t)n_nodes * 50 * sizeof(float), stream);

    edge_kernel<<<(n_edges + BLK_E - 1) / BLK_E, NTHR, 0, stream>>>(
        t, x, Ofx, src, tgt, Wt, B0, B1, B2, B3, B4, Ep, n_edges);

    node_kernel<<<(n_nodes + 63) / 64, 256, 0, stream>>>(
        Ep, OW0, OB0, OW1, OB1, (float*)d_out, n_nodes);
}

// Round 4
// 1586.202 us; speedup vs baseline: 1.2536x; 1.2536x over previous
//
#include <hip/hip_runtime.h>

typedef unsigned short u16;
typedef __attribute__((ext_vector_type(8))) short short8;
typedef __attribute__((ext_vector_type(4))) float f32x4;

constexpr int SA     = 168;   // act row stride (bf16): 336 B -> 2-way banks (free)
constexpr int BLK_E  = 128;   // edges per block
constexpr int NTHR   = 128;   // 2 waves, each owns 64 edges x full N
constexpr int J_MAX  = 10;    // N tiles (160 padded)
constexpr int KS_MAX = 5;     // K steps of 32 (160 padded)
constexpr int CHUNK  = 512;   // elems per (j,ks) fragment chunk = 1 KB
constexpr int WSLOT  = J_MAX * KS_MAX * CHUNK;   // 25600 elems = 51200 B / layer

__device__ __forceinline__ u16 f2bf(float f) {  // RNE f32->bf16
    union { float f; unsigned u; } c; c.f = f;
    return (u16)((c.u + 0x7fffu + ((c.u >> 16) & 1u)) >> 16);
}

// activation k-storage permutation (hidden layers):
//  logical n = j*16+col stored at k' = col*8+j (j<8) | 128+col*2+(j-8) (j=8,9)
__device__ __forceinline__ int kperm(int kp) {
    if (kp < 128) return (kp & 7) * 16 + (kp >> 3);
    if (kp < 160) { const int m = kp - 128; return (8 + (m & 1)) * 16 + (m >> 1); }
    return 1 << 30;
}

// ---- prep: weights -> MFMA fragment order ----------------------------------
// chunk(j,ks) = 1 KB: lane l (= q*16+c), elems e=0..7 hold
//   W^T[n = j*16+c][kphys = ks*32 + q*8 + e]   (kphys permuted for hidden layers)
__global__ void prep_weights(const float* __restrict__ W0, const float* __restrict__ W1,
                             const float* __restrict__ W2, const float* __restrict__ W3,
                             const float* __restrict__ W4, u16* __restrict__ out)
{
    const int l = blockIdx.y;
    const float* W; int DI, DO; bool perm;
    if      (l == 0) { W = W0; DI = 13;  DO = 150; perm = false; }
    else if (l == 1) { W = W1; DI = 150; DO = 150; perm = true;  }
    else if (l == 2) { W = W2; DI = 150; DO = 150; perm = true;  }
    else if (l == 3) { W = W3; DI = 150; DO = 150; perm = true;  }
    else             { W = W4; DI = 150; DO = 50;  perm = true;  }
    u16* dst = out + (size_t)l * WSLOT;
    for (int idx = blockIdx.x * blockDim.x + threadIdx.x; idx < WSLOT;
         idx += gridDim.x * blockDim.x) {
        const int chunk = idx / CHUNK;
        const int within = idx - chunk * CHUNK;
        const int lane = within >> 3, e = within & 7;
        const int j = chunk / KS_MAX, ks = chunk - j * KS_MAX;
        const int c = lane & 15, q = lane >> 4;
        const int n = j * 16 + c;
        const int kphys = ks * 32 + q * 8 + e;
        const int klog = perm ? kperm(kphys) : kphys;
        const float v = (n < DO && klog < DI) ? W[klog * DO + n] : 0.f;
        dst[idx] = f2bf(v);
    }
}

// ---- one MLP layer: A from LDS (wave-private rows), B coalesced from L2 ----
template<int KS, int NT>
__device__ __forceinline__ void gemm_layer(
    const u16* __restrict__ Wl, const u16* actw,
    int lane, int col, int quad, f32x4 (&acc)[4][NT])
{
#pragma unroll
    for (int i = 0; i < 4; ++i)
#pragma unroll
        for (int j = 0; j < NT; ++j)
            acc[i][j] = f32x4{0.f, 0.f, 0.f, 0.f};

    const u16* wbase = Wl + lane * 8;   // lane's 16B within each 1 KB chunk
#pragma unroll
    for (int ks = 0; ks < KS; ++ks) {
        const int koff = ks * 32 + quad * 8;
        short8 Af[4];
#pragma unroll
        for (int i = 0; i < 4; ++i)
            Af[i] = *(const short8*)&actw[(i * 16 + col) * SA + koff];
#pragma unroll
        for (int j = 0; j < NT; ++j) {
            const short8 Bf = *(const short8*)&wbase[(j * KS_MAX + ks) * CHUNK];
#pragma unroll
            for (int i = 0; i < 4; ++i)
                acc[i][j] = __builtin_amdgcn_mfma_f32_16x16x32_bf16(Af[i], Bf, acc[i][j], 0, 0, 0);
        }
    }
}

// ---- epilogue: bias+relu+bf16, k-permuted in-place store (b128 + b32) ------
__device__ __forceinline__ void epilogue(
    u16* actw, const float* __restrict__ bias,
    int col, int quad, f32x4 (&acc)[4][10])
{
    float bb[10];
#pragma unroll
    for (int j = 0; j < 10; ++j) {
        const int n = j * 16 + col;
        bb[j] = (n < 150) ? bias[n] : 0.f;
    }
#pragma unroll
    for (int i = 0; i < 4; ++i)
#pragma unroll
        for (int r = 0; r < 4; ++r) {
            u16* row = &actw[(i * 16 + quad * 4 + r) * SA];
            short8 pk;
#pragma unroll
            for (int j = 0; j < 8; ++j)
                pk[j] = (short)f2bf(fmaxf(acc[i][j][r] + bb[j], 0.f));
            *(short8*)&row[col * 8] = pk;                         // k' = col*8 + j
            const u16 lo = f2bf(fmaxf(acc[i][8][r] + bb[8], 0.f));
            const u16 hi = f2bf(fmaxf(acc[i][9][r] + bb[9], 0.f));
            *(unsigned*)&row[128 + col * 2] =                      // k' = 128+col*2+(j-8)
                (unsigned)lo | ((unsigned)hi << 16);
        }
}

// ------------------------------- Edge kernel --------------------------------
// ZERO barriers: each wave owns edges [wv*64, wv*64+64) — gather, A-reads and
// epilogue writes all touch only that slab.
__global__ __launch_bounds__(NTHR, 2) void edge_kernel(
    const float* __restrict__ t, const float* __restrict__ x, const float* __restrict__ Ofx,
    const int* __restrict__ src, const int* __restrict__ tgt,
    const u16* __restrict__ Wt,
    const float* __restrict__ B0, const float* __restrict__ B1, const float* __restrict__ B2,
    const float* __restrict__ B3, const float* __restrict__ B4,
    float* __restrict__ Ep, int n_edges)
{
    __shared__ __align__(16) u16 act[BLK_E * SA];    // 43008 B -> 3 blocks/CU
    __shared__ int tgt_s[BLK_E];

    const int tid  = threadIdx.x;
    const int lane = tid & 63;
    const int wv   = tid >> 6;
    const int col  = lane & 15;
    const int quad = lane >> 4;

    // ---- gather R' (wave-private rows), packed b128 LDS writes ----
    {
        const int e = tid;
        const long long ge = (long long)blockIdx.x * BLK_E + e;
        const bool valid = ge < n_edges;
        const int s = valid ? src[ge] : 0;
        const int g = valid ? tgt[ge] : 0;
        float v[16];
        const float4 xs = valid ? *(const float4*)&x[(size_t)s * 4] : float4{0, 0, 0, 0};
        const float2 os = valid ? *(const float2*)&Ofx[(size_t)s * 2] : float2{0, 0};
        const float4 xg = valid ? *(const float4*)&x[(size_t)g * 4] : float4{0, 0, 0, 0};
        const float2 og = valid ? *(const float2*)&Ofx[(size_t)g * 2] : float2{0, 0};
        v[0] = xs.x; v[1] = xs.y; v[2] = xs.z; v[3] = xs.w; v[4] = os.x; v[5] = os.y;
        v[6] = xg.x; v[7] = xg.y; v[8] = xg.z; v[9] = xg.w; v[10] = og.x; v[11] = og.y;
        v[12] = valid ? t[0] : 0.f; v[13] = v[14] = v[15] = 0.f;
        short8 c0, c1;
#pragma unroll
        for (int k = 0; k < 8; ++k) { c0[k] = (short)f2bf(v[k]); c1[k] = (short)f2bf(v[k + 8]); }
        u16* row = &act[e * SA];
        *(short8*)&row[0]  = c0;
        *(short8*)&row[8]  = c1;
        *(short8*)&row[16] = short8{0, 0, 0, 0, 0, 0, 0, 0};
        *(short8*)&row[24] = short8{0, 0, 0, 0, 0, 0, 0, 0};
        tgt_s[e] = valid ? g : -1;
    }
    // no __syncthreads: all later reads are wave-private; compiler orders
    // same-wave LDS deps via lgkmcnt.

    u16* actw = act + wv * 64 * SA;
    f32x4 acc[4][10];

    gemm_layer<1, 10>(Wt + 0 * WSLOT, actw, lane, col, quad, acc);   // L0: K=32(13)
    epilogue(actw, B0, col, quad, acc);
    gemm_layer<5, 10>(Wt + 1 * WSLOT, actw, lane, col, quad, acc);   // L1
    epilogue(actw, B1, col, quad, acc);
    gemm_layer<5, 10>(Wt + 2 * WSLOT, actw, lane, col, quad, acc);   // L2
    epilogue(actw, B2, col, quad, acc);
    gemm_layer<5, 10>(Wt + 3 * WSLOT, actw, lane, col, quad, acc);   // L3
    epilogue(actw, B3, col, quad, acc);

    f32x4 acc4[4][4];
    gemm_layer<5, 4>(Wt + 4 * WSLOT, actw, lane, col, quad, acc4);   // L4: ->50(64)

    // ---- scatter-add E into Ep[tgt][50]: 4 nodes x 64 B per instruction ----
#pragma unroll
    for (int j = 0; j < 4; ++j) {
        const int n = j * 16 + col;
        if (n < 50) {
            const float bb = B4[n];
#pragma unroll
            for (int i = 0; i < 4; ++i)
#pragma unroll
                for (int r = 0; r < 4; ++r) {
                    const int g = tgt_s[wv * 64 + i * 16 + quad * 4 + r];
                    if (g >= 0) atomicAdd(&Ep[(size_t)g * 50 + n], acc4[i][j][r] + bb);
                }
        }
    }
}

// ---------------- Node kernel (fp32 VALU — small cost) ----------------------
template<int DI, int DO, bool RELU>
__device__ __forceinline__ void mlp_layer_t(
    const float* __restrict__ W, const float* __restrict__ B,
    float (*in)[64], float (*out)[64], int tid)
{
    const int et = tid & 15;
    const int jt = tid >> 4;
    constexpr int NG = (DO + 15) / 16;

    float acc0[NG], acc1[NG], acc2[NG], acc3[NG];
#pragma unroll
    for (int g = 0; g < NG; ++g) {
        const int j = jt + 16 * g;
        const float bb = (j < DO) ? B[j] : 0.f;
        acc0[g] = bb; acc1[g] = bb; acc2[g] = bb; acc3[g] = bb;
    }
    for (int k = 0; k < DI; ++k) {
        const float4 a = *(const float4*)&in[k][et * 4];
#pragma unroll
        for (int g = 0; g < NG; ++g) {
            const int j = jt + 16 * g;
            const float wv = (j < DO) ? W[k * DO + j] : 0.f;
            acc0[g] = fmaf(a.x, wv, acc0[g]);
            acc1[g] = fmaf(a.y, wv, acc1[g]);
            acc2[g] = fmaf(a.z, wv, acc2[g]);
            acc3[g] = fmaf(a.w, wv, acc3[g]);
        }
    }
#pragma unroll
    for (int g = 0; g < NG; ++g) {
        const int j = jt + 16 * g;
        if (j < DO) {
            float4 v; v.x = acc0[g]; v.y = acc1[g]; v.z = acc2[g]; v.w = acc3[g];
            if (RELU) {
                v.x = fmaxf(v.x, 0.f); v.y = fmaxf(v.y, 0.f);
                v.z = fmaxf(v.z, 0.f); v.w = fmaxf(v.w, 0.f);
            }
            *(float4*)&out[j][et * 4] = v;
        }
    }
}

__global__ __launch_bounds__(256, 2) void node_kernel(
    const float* __restrict__ Eprime,
    const float* __restrict__ W0, const float* __restrict__ B0,
    const float* __restrict__ W1, const float* __restrict__ B1,
    float* __restrict__ P, int n_nodes)
{
    __shared__ float bufA[104][64];
    __shared__ float bufB[104][64];
    const int tid = threadIdx.x;
    const int n0  = blockIdx.x * 64;

    for (int idx = tid; idx < 64 * 50; idx += 256) {
        const int e = idx / 50;
        const int k = idx - e * 50;
        const int n = n0 + e;
        bufA[k][e] = (n < n_nodes) ? Eprime[(size_t)n * 50 + k] : 0.f;
    }
    __syncthreads();
    mlp_layer_t<50, 100, true >(W0, B0, bufA, bufB, tid); __syncthreads();
    mlp_layer_t<100, 4, false>(W1, B1, bufB, bufA, tid); __syncthreads();
    for (int idx = tid; idx < 64 * 4; idx += 256) {
        const int e = idx & 63;
        const int j = idx >> 6;
        const int n = n0 + e;
        if (n < n_nodes) P[(size_t)n * 4 + j] = bufA[j][e];
    }
}

// ------------------------------- launcher -----------------------------------
extern "C" void kernel_launch(void* const* d_in, const int* in_sizes, int n_in,
                              void* d_out, int out_size, void* d_ws, size_t ws_size,
                              hipStream_t stream)
{
    const float* t   = (const float*)d_in[0];
    const float* x   = (const float*)d_in[1];
    const float* Ofx = (const float*)d_in[2];
    const int*   src = (const int*)d_in[3];
    const int*   tgt = (const int*)d_in[4];
    const float* W0  = (const float*)d_in[5];  const float* B0 = (const float*)d_in[6];
    const float* W1  = (const float*)d_in[7];  const float* B1 = (const float*)d_in[8];
    const float* W2  = (const float*)d_in[9];  const float* B2 = (const float*)d_in[10];
    const float* W3  = (const float*)d_in[11]; const float* B3 = (const float*)d_in[12];
    const float* W4  = (const float*)d_in[13]; const float* B4 = (const float*)d_in[14];
    const float* OW0 = (const float*)d_in[15]; const float* OB0 = (const float*)d_in[16];
    const float* OW1 = (const float*)d_in[17]; const float* OB1 = (const float*)d_in[18];

    const int n_nodes = in_sizes[1] / 4;
    const int n_edges = in_sizes[3];

    float* Ep = (float*)d_ws;                                               // [N,50] fp32
    u16*   Wt = (u16*)((char*)d_ws + (size_t)n_nodes * 50 * sizeof(float)); // 5 x 51.2 KB

    prep_weights<<<dim3(32, 5), 256, 0, stream>>>(W0, W1, W2, W3, W4, Wt);
    hipMemsetAsync(Ep, 0, (size_t)n_nodes * 50 * sizeof(float), stream);

    edge_kernel<<<(n_edges + BLK_E - 1) / BLK_E, NTHR, 0, stream>>>(
        t, x, Ofx, src, tgt, Wt, B0, B1, B2, B3, B4, Ep, n_edges);

    node_kernel<<<(n_nodes + 63) / 64, 256, 0, stream>>>(
        Ep, OW0, OB0, OW1, OB1, (float*)d_out, n_nodes);
}